// Round 5
// baseline (898.972 us; speedup 1.0000x reference)
//
#include <hip/hip_runtime.h>

typedef unsigned short u16;
typedef __attribute__((ext_vector_type(8))) short short8;
typedef __attribute__((ext_vector_type(4))) float f32x4;

constexpr int Bn = 8, Cn = 384, Hn = 64, Wn = 64, Tn = Hn * Wn, Mn = Bn * Tn, HIDn = 1536;
constexpr size_t S4 = (size_t)Mn * Cn * 4;   // one fp32 [B,T,C] = 50,331,648 bytes
constexpr size_t S2 = (size_t)Mn * Cn * 2;   // bf16 [B,T,C]
constexpr int NCH = 64, LCH = Tn / NCH;      // 64 chunks x 64 steps
constexpr int NLANE = Bn * NCH * Cn;         // 196608 scan-chunk threads
constexpr int CV = 8;                        // conv outputs per thread (along w)

__device__ __forceinline__ u16 f2bf(float f) {
  unsigned u = __builtin_bit_cast(unsigned, f);
  unsigned r = (u + 0x7fffu + ((u >> 16) & 1u)) >> 16;
  return (u16)r;
}

__device__ __forceinline__ float bf2f(u16 h) {
  return __builtin_bit_cast(float, (unsigned)h << 16);
}

__device__ __forceinline__ void gload16(const u16* g, u16* l) {
  __builtin_amdgcn_global_load_lds(
      (const __attribute__((address_space(1))) unsigned int*)(g),
      (__attribute__((address_space(3))) unsigned int*)(l), 16, 0, 0);
}

// ---------------- transpose x [B,C,T] -> tok [B,T,C] ----------------
__global__ void k_transpose_in(const float* __restrict__ x, float* __restrict__ tok) {
  __shared__ float tile[32][33];
  int b = blockIdx.z, t0 = blockIdx.x * 32, c0 = blockIdx.y * 32;
  int tt = threadIdx.x % 32, cc = threadIdx.x / 32;
  const float* xp = x + ((size_t)b * Cn + c0) * Tn + t0;
  for (int i = 0; i < 32; i += 8) tile[cc + i][tt] = xp[(size_t)(cc + i) * Tn + tt];
  __syncthreads();
  int cw = threadIdx.x % 32, tw = threadIdx.x / 32;
  float* op = tok + ((size_t)b * Tn + t0) * Cn + c0;
  for (int i = 0; i < 32; i += 8) op[(size_t)(tw + i) * Cn + cw] = tile[cw][tw + i];
}

// ---------------- fp32 -> bf16 convert ----------------
__global__ void k_f2bf(const float* __restrict__ in, u16* __restrict__ out, int n) {
  int i = blockIdx.x * 256 + threadIdx.x;
  if (i < n) out[i] = f2bf(in[i]);
}

// ---------------- effective 5x5 depthwise weights, layout [set][tap][C] ----------------
__global__ void k_weff(const float* __restrict__ aA, const float* __restrict__ w1A,
                       const float* __restrict__ w3A, const float* __restrict__ w5A,
                       const float* __restrict__ aF, const float* __restrict__ w1F,
                       const float* __restrict__ w3F, const float* __restrict__ w5F,
                       float* __restrict__ weff) {
  int i = blockIdx.x * 256 + threadIdx.x;
  if (i >= 2 * Cn * 25) return;
  int set = i / (Cn * 25), c = (i / 25) % Cn, ij = i % 25, ki = ij / 5, kj = ij % 5;
  const float* a = set ? aF : aA;
  const float* w1 = set ? w1F : w1A;
  const float* w3 = set ? w3F : w3A;
  const float* w5 = set ? w5F : w5A;
  float v = a[3] * w5[c * 25 + ij];
  if (ki >= 1 && ki <= 3 && kj >= 1 && kj <= 3) v += a[2] * w3[c * 9 + (ki - 1) * 3 + (kj - 1)];
  if (ki == 2 && kj == 2) v += a[1] * w1[c] + a[0];
  weff[(set * 25 + ij) * Cn + c] = v;
}

// ---------------- per-channel total weight sum (interior pixels) ----------------
__global__ void k_sumw(const float* __restrict__ weff, float* __restrict__ sumw) {
  int i = blockIdx.x * 256 + threadIdx.x;  // over 2*Cn
  if (i >= 2 * Cn) return;
  int set = i / Cn, c = i % Cn;
  float s = 0.f;
  for (int t = 0; t < 25; t++) s += weff[(set * 25 + t) * Cn + c];
  sumw[i] = s;
}

// ---------------- fused LN: stats + write normalized x as bf16 ----------------
__global__ void k_lnnorm(const float* __restrict__ tok, u16* __restrict__ xs) {
  int token = blockIdx.x * 4 + (threadIdx.x >> 6);
  int lane = threadIdx.x & 63;
  const float* p = tok + (size_t)token * Cn;
  float v[6];
  float s = 0.f, s2 = 0.f;
#pragma unroll
  for (int j = 0; j < 6; j++) {
    v[j] = p[lane + j * 64];
    s += v[j];
    s2 += v[j] * v[j];
  }
  for (int off = 32; off; off >>= 1) { s += __shfl_xor(s, off); s2 += __shfl_xor(s2, off); }
  float m = s * (1.0f / Cn);
  float r = rsqrtf(s2 * (1.0f / Cn) - m * m + 1e-5f);
  u16* op = xs + (size_t)token * Cn;
#pragma unroll
  for (int j = 0; j < 6; j++) op[lane + j * 64] = f2bf((v[j] - m) * r);
}

// ---------------- 5x5 depthwise conv on normalized x (bf16 in/out) ----------------
// out = g*sum(xhat*w) + b*sum_valid(w). One thread per channel, CV outputs along w.
__global__ __launch_bounds__(384) void k_conv(const u16* __restrict__ xs,
                                              const float* __restrict__ g,
                                              const float* __restrict__ bb,
                                              const float* __restrict__ weff,
                                              const float* __restrict__ sumw,
                                              u16* __restrict__ out) {
  int c = threadIdx.x;
  int w0 = blockIdx.x * CV, h = blockIdx.y, b = blockIdx.z;
  float wv[25];
#pragma unroll
  for (int i = 0; i < 25; i++) wv[i] = weff[i * Cn + c];
  float gc = g[c], bc = bb[c];
  const u16* base = xs + (size_t)b * Tn * Cn + c;
  float acc[CV], sw[CV];
#pragma unroll
  for (int v = 0; v < CV; v++) acc[v] = 0.f;
  bool interior = (h >= 2) && (h <= Hn - 3) && (w0 >= 2) && (w0 + CV + 1 < Wn - 1);
  if (interior) {
#pragma unroll
    for (int ki = 0; ki < 5; ki++) {
      int rowt = (h + ki - 2) * Wn + w0 - 2;
#pragma unroll
      for (int jj = 0; jj < CV + 4; jj++) {
        float y = bf2f(base[(size_t)(rowt + jj) * Cn]);
#pragma unroll
        for (int v = 0; v < CV; v++) {
          int kj = jj - v;
          if (kj >= 0 && kj < 5) acc[v] = fmaf(y, wv[ki * 5 + kj], acc[v]);
        }
      }
    }
    float s0 = sumw[c];
#pragma unroll
    for (int v = 0; v < CV; v++) sw[v] = s0;
  } else {
#pragma unroll
    for (int v = 0; v < CV; v++) sw[v] = 0.f;
#pragma unroll
    for (int ki = 0; ki < 5; ki++) {
      int hh = h + ki - 2;
      if ((unsigned)hh >= (unsigned)Hn) continue;
#pragma unroll
      for (int jj = 0; jj < CV + 4; jj++) {
        int ww = w0 + jj - 2;
        if ((unsigned)ww >= (unsigned)Wn) continue;
        float y = bf2f(base[(size_t)(hh * Wn + ww) * Cn]);
#pragma unroll
        for (int v = 0; v < CV; v++) {
          int kj = jj - v;
          if (kj >= 0 && kj < 5) {
            float wt = wv[ki * 5 + kj];
            acc[v] = fmaf(y, wt, acc[v]);
            sw[v] += wt;
          }
        }
      }
    }
  }
  u16* op = out + ((size_t)b * Tn + (size_t)h * Wn + w0) * Cn + c;
#pragma unroll
  for (int v = 0; v < CV; v++) op[(size_t)v * Cn] = f2bf(gc * acc[v] + bc * sw[v]);
}

// ---------------- bf16 GEMM: C[M,N] = A[M,K] * W[N,K]^T, 128x128 tile ----------------
// MODE 0: fp32 store; 1: sigmoid fp32; 2: relu^2 -> bf16; 3: tok += gamma*val (in place)
template <int MODE>
__global__ __launch_bounds__(256) void k_gemm(const u16* __restrict__ A,
                                              const u16* __restrict__ Wt,
                                              float* __restrict__ outF, u16* __restrict__ outH,
                                              float* __restrict__ tok,
                                              const float* __restrict__ gamma, int K, int N) {
  __shared__ u16 lds_a[128 * 32];
  __shared__ u16 lds_b[128 * 32];
  int tid = threadIdx.x;
  int bm = blockIdx.x * 128, bn = blockIdx.y * 128;
  int wave = tid >> 6, lane = tid & 63;
  int wm = (wave >> 1) * 64, wn = (wave & 1) * 64;
  int lr = lane & 15, kgr = lane >> 4;

  f32x4 acc[4][4];
#pragma unroll
  for (int i = 0; i < 4; i++)
#pragma unroll
    for (int j = 0; j < 4; j++) acc[i][j] = f32x4{0.f, 0.f, 0.f, 0.f};

  int r0 = tid >> 2;
  int kc0 = (tid & 3) * 8;
  for (int k0 = 0; k0 < K; k0 += 32) {
    gload16(A + (size_t)(bm + r0) * K + k0 + kc0, &lds_a[tid * 8]);
    gload16(A + (size_t)(bm + r0 + 64) * K + k0 + kc0, &lds_a[(tid + 256) * 8]);
    gload16(Wt + (size_t)(bn + r0) * K + k0 + kc0, &lds_b[tid * 8]);
    gload16(Wt + (size_t)(bn + r0 + 64) * K + k0 + kc0, &lds_b[(tid + 256) * 8]);
    __syncthreads();
    short8 af[4], bfr[4];
#pragma unroll
    for (int mi = 0; mi < 4; mi++)
      af[mi] = *(const short8*)&lds_a[(wm + mi * 16 + lr) * 32 + kgr * 8];
#pragma unroll
    for (int ni = 0; ni < 4; ni++)
      bfr[ni] = *(const short8*)&lds_b[(wn + ni * 16 + lr) * 32 + kgr * 8];
#pragma unroll
    for (int mi = 0; mi < 4; mi++)
#pragma unroll
      for (int ni = 0; ni < 4; ni++)
        acc[mi][ni] = __builtin_amdgcn_mfma_f32_16x16x32_bf16(af[mi], bfr[ni], acc[mi][ni], 0, 0, 0);
    __syncthreads();
  }

#pragma unroll
  for (int mi = 0; mi < 4; mi++)
#pragma unroll
    for (int ni = 0; ni < 4; ni++) {
#pragma unroll
      for (int r = 0; r < 4; r++) {
        int gr = bm + wm + mi * 16 + kgr * 4 + r;
        int gc = bn + wn + ni * 16 + lr;
        size_t idx = (size_t)gr * N + gc;
        float v = acc[mi][ni][r];
        if (MODE == 0) {
          outF[idx] = v;
        } else if (MODE == 1) {
          outF[idx] = 1.0f / (1.0f + __expf(-v));
        } else if (MODE == 2) {
          float tpos = fmaxf(v, 0.0f);
          outH[idx] = f2bf(tpos * tpos);
        } else if (MODE == 3) {
          tok[idx] = tok[idx] + gamma[gc] * v;
        }
      }
    }
}

// ---------------- chunked WKV scan ----------------
// gid -> (b, ch, c); consecutive c in a wave => coalesced.
// dir 0: row scan, element i of chunk at t = ch*LCH + i, stride Cn
// dir 1: col scan (LCH == Hn), element i at t = i*Wn + ch, stride Wn*Cn

// Phase A: per-chunk local state from zero init (state recurrence only uses w)
__global__ void k_scanA(const float* __restrict__ k, const float* __restrict__ v,
                        const float* __restrict__ decay, int dir,
                        float* __restrict__ SP, float* __restrict__ SQ, float* __restrict__ SO) {
  int gid = blockIdx.x * 256 + threadIdx.x;
  int c = gid % Cn;
  int ch = (gid / Cn) % NCH;
  int b = gid / (Cn * NCH);
  float w = decay[dir * Cn + c] * (1.0f / Tn);
  size_t base = dir ? ((size_t)b * Tn + ch) * Cn + c : ((size_t)b * Tn + ch * LCH) * Cn + c;
  size_t stride = dir ? (size_t)Wn * Cn : (size_t)Cn;
  const float* kp = k + base;
  const float* vp = v + base;
  float p = 0.f, q = 0.f, o = -1e30f;
  float kt = kp[0], vt = vp[0];
  for (int i = 0; i < LCH; i++) {
    float kn = 0.f, vn = 0.f;
    if (i + 1 < LCH) { kn = kp[stride * (i + 1)]; vn = vp[stride * (i + 1)]; }
    float no2 = fmaxf(w + o, kt);
    float A2 = __expf(w + o - no2), B2 = __expf(kt - no2);
    p = A2 * p + B2 * vt;
    q = A2 * q + B2;
    o = no2;
    kt = kn; vt = vn;
  }
  SP[gid] = p; SQ[gid] = q; SO[gid] = o;
}

// Phase B: exclusive combine across chunks, one thread per (b,c)
__global__ void k_scanB(const float* __restrict__ decay, int dir,
                        float* __restrict__ SP, float* __restrict__ SQ, float* __restrict__ SO) {
  int gid = blockIdx.x * 256 + threadIdx.x;  // B*C
  int c = gid % Cn, b = gid / Cn;
  float wL = decay[dir * Cn + c] * (1.0f / Tn) * LCH;
  float p = 0.f, q = 0.f, o = -1e30f;
  for (int ch = 0; ch < NCH; ch++) {
    size_t idx = ((size_t)b * NCH + ch) * Cn + c;
    float lp = SP[idx], lq = SQ[idx], lo = SO[idx];
    SP[idx] = p; SQ[idx] = q; SO[idx] = o;
    float o1 = o + wL;
    float no = fmaxf(o1, lo);
    float e1 = __expf(o1 - no), e2 = __expf(lo - no);
    p = p * e1 + lp * e2;
    q = q * e1 + lq * e2;
    o = no;
  }
}

// Phase C: replay chunk from incoming state, write y into v
__global__ void k_scanC(const float* __restrict__ k, float* __restrict__ v,
                        const float* __restrict__ decay, const float* __restrict__ first, int dir,
                        const float* __restrict__ SP, const float* __restrict__ SQ,
                        const float* __restrict__ SO) {
  int gid = blockIdx.x * 256 + threadIdx.x;
  int c = gid % Cn;
  int ch = (gid / Cn) % NCH;
  int b = gid / (Cn * NCH);
  float w = decay[dir * Cn + c] * (1.0f / Tn);
  float u = first[dir * Cn + c] * (1.0f / Tn);
  size_t base = dir ? ((size_t)b * Tn + ch) * Cn + c : ((size_t)b * Tn + ch * LCH) * Cn + c;
  size_t stride = dir ? (size_t)Wn * Cn : (size_t)Cn;
  const float* kp = k + base;
  float* vp = v + base;
  float p = SP[gid], q = SQ[gid], o = SO[gid];
  float kt = kp[0], vt = vp[0];
  for (int i = 0; i < LCH; i++) {
    float kn = 0.f, vn = 0.f;
    if (i + 1 < LCH) { kn = kp[stride * (i + 1)]; vn = vp[stride * (i + 1)]; }
    float no = fmaxf(o, u + kt);
    float Aa = __expf(o - no), Bb = __expf(u + kt - no);
    float y = (Aa * p + Bb * vt) / (Aa * q + Bb);
    vp[stride * i] = y;
    float no2 = fmaxf(w + o, kt);
    float A2 = __expf(w + o - no2), B2 = __expf(kt - no2);
    p = A2 * p + B2 * vt;
    q = A2 * q + B2;
    o = no2;
    kt = kn; vt = vn;
  }
}

// ---------------- a2 = bf16(sr * wkv) ----------------
__global__ void k_mulbf(const float* __restrict__ r, const float* __restrict__ v,
                        u16* __restrict__ out, int n) {
  int i = blockIdx.x * 256 + threadIdx.x;
  if (i < n) out[i] = f2bf(r[i] * v[i]);
}

// ---------------- final: tok2 = tok1 + gamma2*(rr*kv), transpose to NCHW ----------------
__global__ void k_final(const float* __restrict__ tok1, const float* __restrict__ rr,
                        const float* __restrict__ kv, const float* __restrict__ gamma2,
                        float* __restrict__ out) {
  __shared__ float tile[32][33];
  int b = blockIdx.z, t0 = blockIdx.x * 32, c0 = blockIdx.y * 32;
  int cc = threadIdx.x % 32, tt0 = threadIdx.x / 32;
  size_t base = ((size_t)b * Tn + t0) * Cn + c0;
  float gam = gamma2[c0 + cc];
  for (int i = 0; i < 32; i += 8) {
    size_t idx = base + (size_t)(tt0 + i) * Cn + cc;
    tile[tt0 + i][cc] = tok1[idx] + gam * (rr[idx] * kv[idx]);
  }
  __syncthreads();
  int tw = threadIdx.x % 32, cwi = threadIdx.x / 32;
  float* op = out + ((size_t)b * Cn + c0) * Tn + t0;
  for (int i = 0; i < 32; i += 8) op[(size_t)(cwi + i) * Tn + tw] = tile[tw][cwi + i];
}

extern "C" void kernel_launch(void* const* d_in, const int* in_sizes, int n_in, void* d_out,
                              int out_size, void* d_ws, size_t ws_size, hipStream_t stream) {
  const float* x = (const float*)d_in[0];
  const float* ln1_g = (const float*)d_in[1];
  const float* ln1_b = (const float*)d_in[2];
  const float* ln2_g = (const float*)d_in[3];
  const float* ln2_b = (const float*)d_in[4];
  const float* gamma1 = (const float*)d_in[5];
  const float* gamma2 = (const float*)d_in[6];
  const float* att_alpha = (const float*)d_in[7];
  const float* att_w1 = (const float*)d_in[8];
  const float* att_w3 = (const float*)d_in[9];
  const float* att_w5 = (const float*)d_in[10];
  const float* att_wk = (const float*)d_in[11];
  const float* att_wv = (const float*)d_in[12];
  const float* att_wr = (const float*)d_in[13];
  const float* att_wo = (const float*)d_in[14];
  const float* sp_decay = (const float*)d_in[15];
  const float* sp_first = (const float*)d_in[16];
  const float* ffn_alpha = (const float*)d_in[17];
  const float* ffn_w1 = (const float*)d_in[18];
  const float* ffn_w3 = (const float*)d_in[19];
  const float* ffn_w5 = (const float*)d_in[20];
  const float* ffn_wk = (const float*)d_in[21];
  const float* ffn_wv = (const float*)d_in[22];
  const float* ffn_wr = (const float*)d_in[23];
  float* out = (float*)d_out;

  char* ws = (char*)d_ws;
  float* TOK = (float*)(ws);
  float* KB = (float*)(ws + S4);
  float* VB = (float*)(ws + 2 * S4);
  float* RB = (float*)(ws + 3 * S4);
  u16* ABF = (u16*)(ws + 4 * S4);
  u16* KKB = (u16*)(ws + 2 * S4);   // alias VB+RB (dead by then); exactly 2*S4 bytes
  float* RR = VB;                   // rr written over KKB's first half after G4
  u16* XS = (u16*)(ws + S4);        // normalized-x bf16, aliases KB (dead during lnnorm+conv)
  // scan state buffers alias ABF (dead during scans; k_mulbf regenerates ABF after)
  float* SP = (float*)(ws + 4 * S4);
  float* SQ = SP + NLANE;
  float* SO = SQ + NLANE;
  size_t W0 = 4 * S4 + S2;
  u16* wkb = (u16*)(ws + W0);
  u16* wvb = (u16*)(ws + W0 + 294912);
  u16* wrb = (u16*)(ws + W0 + 2 * 294912);
  u16* wob = (u16*)(ws + W0 + 3 * 294912);
  u16* fwkb = (u16*)(ws + W0 + 4 * 294912);
  u16* fwvb = (u16*)(ws + W0 + 4 * 294912 + 1179648);
  u16* fwrb = (u16*)(ws + W0 + 4 * 294912 + 2 * 1179648);
  float* WEFF = (float*)(ws + W0 + 4 * 294912 + 2 * 1179648 + 294912);
  float* SUMW = WEFF + 2 * Cn * 25;

  const int CC = Cn * Cn;            // 147456
  const int CH = Cn * HIDn;          // 589824
  k_f2bf<<<CC / 256, 256, 0, stream>>>(att_wk, wkb, CC);
  k_f2bf<<<CC / 256, 256, 0, stream>>>(att_wv, wvb, CC);
  k_f2bf<<<CC / 256, 256, 0, stream>>>(att_wr, wrb, CC);
  k_f2bf<<<CC / 256, 256, 0, stream>>>(att_wo, wob, CC);
  k_f2bf<<<CH / 256, 256, 0, stream>>>(ffn_wk, fwkb, CH);
  k_f2bf<<<CH / 256, 256, 0, stream>>>(ffn_wv, fwvb, CH);
  k_f2bf<<<CC / 256, 256, 0, stream>>>(ffn_wr, fwrb, CC);
  k_weff<<<(2 * Cn * 25 + 255) / 256, 256, 0, stream>>>(att_alpha, att_w1, att_w3, att_w5,
                                                        ffn_alpha, ffn_w1, ffn_w3, ffn_w5, WEFF);
  k_sumw<<<3, 256, 0, stream>>>(WEFF, SUMW);
  k_transpose_in<<<dim3(Tn / 32, Cn / 32, Bn), 256, 0, stream>>>(x, TOK);

  // ---- attention half ----
  k_lnnorm<<<Mn / 4, 256, 0, stream>>>(TOK, XS);
  dim3 gconv(Wn / CV, Hn, Bn);
  k_conv<<<gconv, Cn, 0, stream>>>(XS, ln1_g, ln1_b, WEFF, SUMW, ABF);
  dim3 g1(Mn / 128, Cn / 128);
  k_gemm<0><<<g1, 256, 0, stream>>>(ABF, wkb, KB, nullptr, nullptr, nullptr, Cn, Cn);
  k_gemm<0><<<g1, 256, 0, stream>>>(ABF, wvb, VB, nullptr, nullptr, nullptr, Cn, Cn);
  k_gemm<1><<<g1, 256, 0, stream>>>(ABF, wrb, RB, nullptr, nullptr, nullptr, Cn, Cn);

  // ---- chunked WKV scans (row then col) ----
  int gsc = NLANE / 256;  // 768 blocks
  k_scanA<<<gsc, 256, 0, stream>>>(KB, VB, sp_decay, 0, SP, SQ, SO);
  k_scanB<<<Bn * Cn / 256, 256, 0, stream>>>(sp_decay, 0, SP, SQ, SO);
  k_scanC<<<gsc, 256, 0, stream>>>(KB, VB, sp_decay, sp_first, 0, SP, SQ, SO);
  k_scanA<<<gsc, 256, 0, stream>>>(KB, VB, sp_decay, 1, SP, SQ, SO);
  k_scanB<<<Bn * Cn / 256, 256, 0, stream>>>(sp_decay, 1, SP, SQ, SO);
  k_scanC<<<gsc, 256, 0, stream>>>(KB, VB, sp_decay, sp_first, 1, SP, SQ, SO);

  k_mulbf<<<(size_t)Mn * Cn / 256, 256, 0, stream>>>(RB, VB, ABF, Mn * Cn);
  k_gemm<3><<<g1, 256, 0, stream>>>(ABF, wob, nullptr, nullptr, TOK, gamma1, Cn, Cn);

  // ---- FFN half ----
  k_lnnorm<<<Mn / 4, 256, 0, stream>>>(TOK, XS);
  k_conv<<<gconv, Cn, 0, stream>>>(XS, ln2_g, ln2_b, WEFF + 25 * Cn, SUMW + Cn, ABF);
  dim3 g3(Mn / 128, HIDn / 128);
  k_gemm<2><<<g3, 256, 0, stream>>>(ABF, fwkb, nullptr, KKB, nullptr, nullptr, Cn, HIDn);
  k_gemm<0><<<g1, 256, 0, stream>>>(KKB, fwvb, KB, nullptr, nullptr, nullptr, HIDn, Cn);
  k_gemm<1><<<g1, 256, 0, stream>>>(ABF, fwrb, RR, nullptr, nullptr, nullptr, Cn, Cn);
  k_final<<<dim3(Tn / 32, Cn / 32, Bn), 256, 0, stream>>>(TOK, RR, KB, gamma2, out);
}

// Round 6
// 551.851 us; speedup vs baseline: 1.6290x; 1.6290x over previous
//
#include <hip/hip_runtime.h>

typedef unsigned short u16;
typedef __attribute__((ext_vector_type(8))) short short8;
typedef __attribute__((ext_vector_type(4))) float f32x4;
typedef __attribute__((ext_vector_type(4))) unsigned short u16x4;

constexpr int Bn = 8, Cn = 384, Hn = 64, Wn = 64, Tn = Hn * Wn, Mn = Bn * Tn, HIDn = 1536;
constexpr size_t S4 = (size_t)Mn * Cn * 4;   // one fp32 [B,T,C] = 50,331,648 bytes
constexpr size_t S2 = (size_t)Mn * Cn * 2;   // bf16 [B,T,C]
constexpr int NCH = 64, LCH = Tn / NCH;      // 64 chunks x 64 steps
constexpr int NLANE = Bn * NCH * Cn;         // 196608 scan-chunk threads
constexpr int CV = 8;                        // conv outputs per chunk (along w)

__device__ __forceinline__ u16 f2bf(float f) {
  unsigned u = __builtin_bit_cast(unsigned, f);
  unsigned r = (u + 0x7fffu + ((u >> 16) & 1u)) >> 16;
  return (u16)r;
}

__device__ __forceinline__ float bf2f(u16 h) {
  return __builtin_bit_cast(float, (unsigned)h << 16);
}

__device__ __forceinline__ void gload16(const u16* g, u16* l) {
  __builtin_amdgcn_global_load_lds(
      (const __attribute__((address_space(1))) unsigned int*)(g),
      (__attribute__((address_space(3))) unsigned int*)(l), 16, 0, 0);
}

// ---------------- transpose x [B,C,T] -> tok [B,T,C] ----------------
__global__ void k_transpose_in(const float* __restrict__ x, float* __restrict__ tok) {
  __shared__ float tile[32][33];
  int b = blockIdx.z, t0 = blockIdx.x * 32, c0 = blockIdx.y * 32;
  int tt = threadIdx.x % 32, cc = threadIdx.x / 32;
  const float* xp = x + ((size_t)b * Cn + c0) * Tn + t0;
  for (int i = 0; i < 32; i += 8) tile[cc + i][tt] = xp[(size_t)(cc + i) * Tn + tt];
  __syncthreads();
  int cw = threadIdx.x % 32, tw = threadIdx.x / 32;
  float* op = tok + ((size_t)b * Tn + t0) * Cn + c0;
  for (int i = 0; i < 32; i += 8) op[(size_t)(tw + i) * Cn + cw] = tile[cw][tw + i];
}

// ---------------- fp32 -> bf16 convert ----------------
__global__ void k_f2bf(const float* __restrict__ in, u16* __restrict__ out, int n) {
  int i = blockIdx.x * 256 + threadIdx.x;
  if (i < n) out[i] = f2bf(in[i]);
}

// ---------------- effective 5x5 depthwise weights, layout [set][tap][C] ----------------
__global__ void k_weff(const float* __restrict__ aA, const float* __restrict__ w1A,
                       const float* __restrict__ w3A, const float* __restrict__ w5A,
                       const float* __restrict__ aF, const float* __restrict__ w1F,
                       const float* __restrict__ w3F, const float* __restrict__ w5F,
                       float* __restrict__ weff) {
  int i = blockIdx.x * 256 + threadIdx.x;
  if (i >= 2 * Cn * 25) return;
  int set = i / (Cn * 25), c = (i / 25) % Cn, ij = i % 25, ki = ij / 5, kj = ij % 5;
  const float* a = set ? aF : aA;
  const float* w1 = set ? w1F : w1A;
  const float* w3 = set ? w3F : w3A;
  const float* w5 = set ? w5F : w5A;
  float v = a[3] * w5[c * 25 + ij];
  if (ki >= 1 && ki <= 3 && kj >= 1 && kj <= 3) v += a[2] * w3[c * 9 + (ki - 1) * 3 + (kj - 1)];
  if (ki == 2 && kj == 2) v += a[1] * w1[c] + a[0];
  weff[(set * 25 + ij) * Cn + c] = v;
}

// ---------------- per-channel total weight sum (interior pixels) ----------------
__global__ void k_sumw(const float* __restrict__ weff, float* __restrict__ sumw) {
  int i = blockIdx.x * 256 + threadIdx.x;  // over 2*Cn
  if (i >= 2 * Cn) return;
  int set = i / Cn, c = i % Cn;
  float s = 0.f;
  for (int t = 0; t < 25; t++) s += weff[(set * 25 + t) * Cn + c];
  sumw[i] = s;
}

// ---------------- fused LN: stats + write normalized x as bf16 ----------------
__global__ void k_lnnorm(const float* __restrict__ tok, u16* __restrict__ xs) {
  int token = blockIdx.x * 4 + (threadIdx.x >> 6);
  int lane = threadIdx.x & 63;
  const float* p = tok + (size_t)token * Cn;
  float v[6];
  float s = 0.f, s2 = 0.f;
#pragma unroll
  for (int j = 0; j < 6; j++) {
    v[j] = p[lane + j * 64];
    s += v[j];
    s2 += v[j] * v[j];
  }
  for (int off = 32; off; off >>= 1) { s += __shfl_xor(s, off); s2 += __shfl_xor(s2, off); }
  float m = s * (1.0f / Cn);
  float r = rsqrtf(s2 * (1.0f / Cn) - m * m + 1e-5f);
  u16* op = xs + (size_t)token * Cn;
#pragma unroll
  for (int j = 0; j < 6; j++) op[lane + j * 64] = f2bf((v[j] - m) * r);
}

// ---------------- 5x5 depthwise conv on normalized x (bf16 in/out) ----------------
// One block per (b,h) row: 384 threads (one per channel), 8 chunks of CV outputs.
// out = g*sum(xhat*w) + b*sum_valid(w).
__global__ __launch_bounds__(384) void k_conv(const u16* __restrict__ xs,
                                              const float* __restrict__ g,
                                              const float* __restrict__ bb,
                                              const float* __restrict__ weff,
                                              const float* __restrict__ sumw,
                                              u16* __restrict__ out) {
  int c = threadIdx.x;
  int h = blockIdx.x, b = blockIdx.y;
  float gc = g[c], bc = bb[c], s0 = sumw[c];
  float wv[25];
#pragma unroll
  for (int i = 0; i < 25; i++) wv[i] = weff[i * Cn + c];
  const u16* base = xs + (size_t)b * Tn * Cn + c;
  u16* orow = out + ((size_t)b * Tn + (size_t)h * Wn) * Cn + c;
  bool hOK = (h >= 2 && h <= Hn - 3);
  for (int w0 = 0; w0 < Wn; w0 += CV) {
    float acc[CV];
#pragma unroll
    for (int v = 0; v < CV; v++) acc[v] = 0.f;
    if (hOK && w0 != 0 && w0 != Wn - CV) {
      // fast path: all 25 taps valid for every output in the chunk
#pragma unroll
      for (int ki = 0; ki < 5; ki++) {
        int rowt = (h + ki - 2) * Wn + w0 - 2;
#pragma unroll
        for (int jj = 0; jj < CV + 4; jj++) {
          float y = bf2f(base[(size_t)(rowt + jj) * Cn]);
#pragma unroll
          for (int v = 0; v < CV; v++) {
            int kj = jj - v;
            if (kj >= 0 && kj < 5) acc[v] = fmaf(y, wv[ki * 5 + kj], acc[v]);
          }
        }
      }
      u16* op = orow + (size_t)w0 * Cn;
#pragma unroll
      for (int v = 0; v < CV; v++) op[(size_t)v * Cn] = f2bf(gc * acc[v] + bc * s0);
    } else {
      float sw[CV];
#pragma unroll
      for (int v = 0; v < CV; v++) sw[v] = 0.f;
#pragma unroll
      for (int ki = 0; ki < 5; ki++) {
        int hh = h + ki - 2;
        if ((unsigned)hh >= (unsigned)Hn) continue;
#pragma unroll
        for (int jj = 0; jj < CV + 4; jj++) {
          int ww = w0 + jj - 2;
          if ((unsigned)ww >= (unsigned)Wn) continue;
          float y = bf2f(base[(size_t)(hh * Wn + ww) * Cn]);
#pragma unroll
          for (int v = 0; v < CV; v++) {
            int kj = jj - v;
            if (kj >= 0 && kj < 5) {
              float wt = wv[ki * 5 + kj];
              acc[v] = fmaf(y, wt, acc[v]);
              sw[v] += wt;
            }
          }
        }
      }
      u16* op = orow + (size_t)w0 * Cn;
#pragma unroll
      for (int v = 0; v < CV; v++) op[(size_t)v * Cn] = f2bf(gc * acc[v] + bc * sw[v]);
    }
  }
}

// ---------------- bf16 GEMM: C[M,N] = A[M,K] * W[N,K]^T, 128x128 tile ----------------
// MODE 0: fp32 store; 1: sigmoid fp32; 2: relu^2 -> bf16; 3: tok += gamma*val (in place)
template <int MODE>
__global__ __launch_bounds__(256) void k_gemm(const u16* __restrict__ A,
                                              const u16* __restrict__ Wt,
                                              float* __restrict__ outF, u16* __restrict__ outH,
                                              float* __restrict__ tok,
                                              const float* __restrict__ gamma, int K, int N) {
  __shared__ u16 lds_a[128 * 32];
  __shared__ u16 lds_b[128 * 32];
  int tid = threadIdx.x;
  int bm = blockIdx.x * 128, bn = blockIdx.y * 128;
  int wave = tid >> 6, lane = tid & 63;
  int wm = (wave >> 1) * 64, wn = (wave & 1) * 64;
  int lr = lane & 15, kgr = lane >> 4;

  f32x4 acc[4][4];
#pragma unroll
  for (int i = 0; i < 4; i++)
#pragma unroll
    for (int j = 0; j < 4; j++) acc[i][j] = f32x4{0.f, 0.f, 0.f, 0.f};

  int r0 = tid >> 2;
  int kc0 = (tid & 3) * 8;
  for (int k0 = 0; k0 < K; k0 += 32) {
    gload16(A + (size_t)(bm + r0) * K + k0 + kc0, &lds_a[tid * 8]);
    gload16(A + (size_t)(bm + r0 + 64) * K + k0 + kc0, &lds_a[(tid + 256) * 8]);
    gload16(Wt + (size_t)(bn + r0) * K + k0 + kc0, &lds_b[tid * 8]);
    gload16(Wt + (size_t)(bn + r0 + 64) * K + k0 + kc0, &lds_b[(tid + 256) * 8]);
    __syncthreads();
    short8 af[4], bfr[4];
#pragma unroll
    for (int mi = 0; mi < 4; mi++)
      af[mi] = *(const short8*)&lds_a[(wm + mi * 16 + lr) * 32 + kgr * 8];
#pragma unroll
    for (int ni = 0; ni < 4; ni++)
      bfr[ni] = *(const short8*)&lds_b[(wn + ni * 16 + lr) * 32 + kgr * 8];
#pragma unroll
    for (int mi = 0; mi < 4; mi++)
#pragma unroll
      for (int ni = 0; ni < 4; ni++)
        acc[mi][ni] = __builtin_amdgcn_mfma_f32_16x16x32_bf16(af[mi], bfr[ni], acc[mi][ni], 0, 0, 0);
    __syncthreads();
  }

#pragma unroll
  for (int mi = 0; mi < 4; mi++)
#pragma unroll
    for (int ni = 0; ni < 4; ni++) {
#pragma unroll
      for (int r = 0; r < 4; r++) {
        int gr = bm + wm + mi * 16 + kgr * 4 + r;
        int gc = bn + wn + ni * 16 + lr;
        size_t idx = (size_t)gr * N + gc;
        float v = acc[mi][ni][r];
        if (MODE == 0) {
          outF[idx] = v;
        } else if (MODE == 1) {
          outF[idx] = 1.0f / (1.0f + __expf(-v));
        } else if (MODE == 2) {
          float tpos = fmaxf(v, 0.0f);
          outH[idx] = f2bf(tpos * tpos);
        } else if (MODE == 3) {
          tok[idx] = tok[idx] + gamma[gc] * v;
        }
      }
    }
}

// ---------------- chunked WKV scan ----------------
// gid -> (b, ch, c); consecutive c in a wave => coalesced.
// dir 0: row scan, element i of chunk at t = ch*LCH + i, stride Cn
// dir 1: col scan (LCH == Hn), element i at t = i*Wn + ch, stride Wn*Cn

// Phase A: per-chunk local state from zero init (state recurrence only uses w)
__global__ void k_scanA(const float* __restrict__ k, const float* __restrict__ v,
                        const float* __restrict__ decay, int dir,
                        float* __restrict__ SP, float* __restrict__ SQ, float* __restrict__ SO) {
  int gid = blockIdx.x * 256 + threadIdx.x;
  int c = gid % Cn;
  int ch = (gid / Cn) % NCH;
  int b = gid / (Cn * NCH);
  float w = decay[dir * Cn + c] * (1.0f / Tn);
  size_t base = dir ? ((size_t)b * Tn + ch) * Cn + c : ((size_t)b * Tn + ch * LCH) * Cn + c;
  size_t stride = dir ? (size_t)Wn * Cn : (size_t)Cn;
  const float* kp = k + base;
  const float* vp = v + base;
  float p = 0.f, q = 0.f, o = -1e30f;
  float kt = kp[0], vt = vp[0];
  for (int i = 0; i < LCH; i++) {
    float kn = 0.f, vn = 0.f;
    if (i + 1 < LCH) { kn = kp[stride * (i + 1)]; vn = vp[stride * (i + 1)]; }
    float no2 = fmaxf(w + o, kt);
    float A2 = __expf(w + o - no2), B2 = __expf(kt - no2);
    p = A2 * p + B2 * vt;
    q = A2 * q + B2;
    o = no2;
    kt = kn; vt = vn;
  }
  SP[gid] = p; SQ[gid] = q; SO[gid] = o;
}

// Phase B: exclusive combine across chunks, one thread per (b,c)
__global__ void k_scanB(const float* __restrict__ decay, int dir,
                        float* __restrict__ SP, float* __restrict__ SQ, float* __restrict__ SO) {
  int gid = blockIdx.x * 256 + threadIdx.x;  // B*C
  int c = gid % Cn, b = gid / Cn;
  float wL = decay[dir * Cn + c] * (1.0f / Tn) * LCH;
  float p = 0.f, q = 0.f, o = -1e30f;
  for (int ch = 0; ch < NCH; ch++) {
    size_t idx = ((size_t)b * NCH + ch) * Cn + c;
    float lp = SP[idx], lq = SQ[idx], lo = SO[idx];
    SP[idx] = p; SQ[idx] = q; SO[idx] = o;
    float o1 = o + wL;
    float no = fmaxf(o1, lo);
    float e1 = __expf(o1 - no), e2 = __expf(lo - no);
    p = p * e1 + lp * e2;
    q = q * e1 + lq * e2;
    o = no;
  }
}

// Phase C: replay chunk from incoming state, write y into v
__global__ void k_scanC(const float* __restrict__ k, float* __restrict__ v,
                        const float* __restrict__ decay, const float* __restrict__ first, int dir,
                        const float* __restrict__ SP, const float* __restrict__ SQ,
                        const float* __restrict__ SO) {
  int gid = blockIdx.x * 256 + threadIdx.x;
  int c = gid % Cn;
  int ch = (gid / Cn) % NCH;
  int b = gid / (Cn * NCH);
  float w = decay[dir * Cn + c] * (1.0f / Tn);
  float u = first[dir * Cn + c] * (1.0f / Tn);
  size_t base = dir ? ((size_t)b * Tn + ch) * Cn + c : ((size_t)b * Tn + ch * LCH) * Cn + c;
  size_t stride = dir ? (size_t)Wn * Cn : (size_t)Cn;
  const float* kp = k + base;
  float* vp = v + base;
  float p = SP[gid], q = SQ[gid], o = SO[gid];
  float kt = kp[0], vt = vp[0];
  for (int i = 0; i < LCH; i++) {
    float kn = 0.f, vn = 0.f;
    if (i + 1 < LCH) { kn = kp[stride * (i + 1)]; vn = vp[stride * (i + 1)]; }
    float no = fmaxf(o, u + kt);
    float Aa = __expf(o - no), Bb = __expf(u + kt - no);
    float y = (Aa * p + Bb * vt) / (Aa * q + Bb);
    vp[stride * i] = y;
    float no2 = fmaxf(w + o, kt);
    float A2 = __expf(w + o - no2), B2 = __expf(kt - no2);
    p = A2 * p + B2 * vt;
    q = A2 * q + B2;
    o = no2;
    kt = kn; vt = vn;
  }
}

// ---------------- a2 = bf16(sr * wkv), vectorized grid-stride ----------------
__global__ void k_mulbf(const float* __restrict__ r, const float* __restrict__ v,
                        u16* __restrict__ out, int n4) {
  int stride = gridDim.x * blockDim.x;
  for (int i = blockIdx.x * blockDim.x + threadIdx.x; i < n4; i += stride) {
    f32x4 a = *(const f32x4*)(r + (size_t)i * 4);
    f32x4 bv = *(const f32x4*)(v + (size_t)i * 4);
    u16x4 o;
#pragma unroll
    for (int j = 0; j < 4; j++) o[j] = f2bf(a[j] * bv[j]);
    *(u16x4*)(out + (size_t)i * 4) = o;
  }
}

// ---------------- final: tok2 = tok1 + gamma2*(rr*kv), transpose to NCHW ----------------
__global__ void k_final(const float* __restrict__ tok1, const float* __restrict__ rr,
                        const float* __restrict__ kv, const float* __restrict__ gamma2,
                        float* __restrict__ out) {
  __shared__ float tile[32][33];
  int b = blockIdx.z, t0 = blockIdx.x * 32, c0 = blockIdx.y * 32;
  int cc = threadIdx.x % 32, tt0 = threadIdx.x / 32;
  size_t base = ((size_t)b * Tn + t0) * Cn + c0;
  float gam = gamma2[c0 + cc];
  for (int i = 0; i < 32; i += 8) {
    size_t idx = base + (size_t)(tt0 + i) * Cn + cc;
    tile[tt0 + i][cc] = tok1[idx] + gam * (rr[idx] * kv[idx]);
  }
  __syncthreads();
  int tw = threadIdx.x % 32, cwi = threadIdx.x / 32;
  float* op = out + ((size_t)b * Cn + c0) * Tn + t0;
  for (int i = 0; i < 32; i += 8) op[(size_t)(cwi + i) * Tn + tw] = tile[tw][cwi + i];
}

extern "C" void kernel_launch(void* const* d_in, const int* in_sizes, int n_in, void* d_out,
                              int out_size, void* d_ws, size_t ws_size, hipStream_t stream) {
  const float* x = (const float*)d_in[0];
  const float* ln1_g = (const float*)d_in[1];
  const float* ln1_b = (const float*)d_in[2];
  const float* ln2_g = (const float*)d_in[3];
  const float* ln2_b = (const float*)d_in[4];
  const float* gamma1 = (const float*)d_in[5];
  const float* gamma2 = (const float*)d_in[6];
  const float* att_alpha = (const float*)d_in[7];
  const float* att_w1 = (const float*)d_in[8];
  const float* att_w3 = (const float*)d_in[9];
  const float* att_w5 = (const float*)d_in[10];
  const float* att_wk = (const float*)d_in[11];
  const float* att_wv = (const float*)d_in[12];
  const float* att_wr = (const float*)d_in[13];
  const float* att_wo = (const float*)d_in[14];
  const float* sp_decay = (const float*)d_in[15];
  const float* sp_first = (const float*)d_in[16];
  const float* ffn_alpha = (const float*)d_in[17];
  const float* ffn_w1 = (const float*)d_in[18];
  const float* ffn_w3 = (const float*)d_in[19];
  const float* ffn_w5 = (const float*)d_in[20];
  const float* ffn_wk = (const float*)d_in[21];
  const float* ffn_wv = (const float*)d_in[22];
  const float* ffn_wr = (const float*)d_in[23];
  float* out = (float*)d_out;

  char* ws = (char*)d_ws;
  float* TOK = (float*)(ws);
  float* KB = (float*)(ws + S4);
  float* VB = (float*)(ws + 2 * S4);
  float* RB = (float*)(ws + 3 * S4);
  u16* ABF = (u16*)(ws + 4 * S4);
  u16* KKB = (u16*)(ws + 2 * S4);   // alias VB+RB (dead by then); exactly 2*S4 bytes
  float* RR = VB;                   // rr written over KKB's first half after G4
  u16* XS = (u16*)(ws + S4);        // normalized-x bf16, aliases KB (dead during lnnorm+conv)
  // scan state buffers alias ABF (dead during scans; k_mulbf regenerates ABF after)
  float* SP = (float*)(ws + 4 * S4);
  float* SQ = SP + NLANE;
  float* SO = SQ + NLANE;
  size_t W0 = 4 * S4 + S2;
  u16* wkb = (u16*)(ws + W0);
  u16* wvb = (u16*)(ws + W0 + 294912);
  u16* wrb = (u16*)(ws + W0 + 2 * 294912);
  u16* wob = (u16*)(ws + W0 + 3 * 294912);
  u16* fwkb = (u16*)(ws + W0 + 4 * 294912);
  u16* fwvb = (u16*)(ws + W0 + 4 * 294912 + 1179648);
  u16* fwrb = (u16*)(ws + W0 + 4 * 294912 + 2 * 1179648);
  float* WEFF = (float*)(ws + W0 + 4 * 294912 + 2 * 1179648 + 294912);
  float* SUMW = WEFF + 2 * Cn * 25;

  const int CC = Cn * Cn;            // 147456
  const int CH = Cn * HIDn;          // 589824
  k_f2bf<<<CC / 256, 256, 0, stream>>>(att_wk, wkb, CC);
  k_f2bf<<<CC / 256, 256, 0, stream>>>(att_wv, wvb, CC);
  k_f2bf<<<CC / 256, 256, 0, stream>>>(att_wr, wrb, CC);
  k_f2bf<<<CC / 256, 256, 0, stream>>>(att_wo, wob, CC);
  k_f2bf<<<CH / 256, 256, 0, stream>>>(ffn_wk, fwkb, CH);
  k_f2bf<<<CH / 256, 256, 0, stream>>>(ffn_wv, fwvb, CH);
  k_f2bf<<<CC / 256, 256, 0, stream>>>(ffn_wr, fwrb, CC);
  k_weff<<<(2 * Cn * 25 + 255) / 256, 256, 0, stream>>>(att_alpha, att_w1, att_w3, att_w5,
                                                        ffn_alpha, ffn_w1, ffn_w3, ffn_w5, WEFF);
  k_sumw<<<3, 256, 0, stream>>>(WEFF, SUMW);
  k_transpose_in<<<dim3(Tn / 32, Cn / 32, Bn), 256, 0, stream>>>(x, TOK);

  // ---- attention half ----
  k_lnnorm<<<Mn / 4, 256, 0, stream>>>(TOK, XS);
  dim3 gconv(Hn, Bn);
  k_conv<<<gconv, Cn, 0, stream>>>(XS, ln1_g, ln1_b, WEFF, SUMW, ABF);
  dim3 g1(Mn / 128, Cn / 128);
  k_gemm<0><<<g1, 256, 0, stream>>>(ABF, wkb, KB, nullptr, nullptr, nullptr, Cn, Cn);
  k_gemm<0><<<g1, 256, 0, stream>>>(ABF, wvb, VB, nullptr, nullptr, nullptr, Cn, Cn);
  k_gemm<1><<<g1, 256, 0, stream>>>(ABF, wrb, RB, nullptr, nullptr, nullptr, Cn, Cn);

  // ---- chunked WKV scans (row then col) ----
  int gsc = NLANE / 256;  // 768 blocks
  k_scanA<<<gsc, 256, 0, stream>>>(KB, VB, sp_decay, 0, SP, SQ, SO);
  k_scanB<<<Bn * Cn / 256, 256, 0, stream>>>(sp_decay, 0, SP, SQ, SO);
  k_scanC<<<gsc, 256, 0, stream>>>(KB, VB, sp_decay, sp_first, 0, SP, SQ, SO);
  k_scanA<<<gsc, 256, 0, stream>>>(KB, VB, sp_decay, 1, SP, SQ, SO);
  k_scanB<<<Bn * Cn / 256, 256, 0, stream>>>(sp_decay, 1, SP, SQ, SO);
  k_scanC<<<gsc, 256, 0, stream>>>(KB, VB, sp_decay, sp_first, 1, SP, SQ, SO);

  k_mulbf<<<2048, 256, 0, stream>>>(RB, VB, ABF, Mn * Cn / 4);
  k_gemm<3><<<g1, 256, 0, stream>>>(ABF, wob, nullptr, nullptr, TOK, gamma1, Cn, Cn);

  // ---- FFN half ----
  k_lnnorm<<<Mn / 4, 256, 0, stream>>>(TOK, XS);
  k_conv<<<gconv, Cn, 0, stream>>>(XS, ln2_g, ln2_b, WEFF + 25 * Cn, SUMW + Cn, ABF);
  dim3 g3(Mn / 128, HIDn / 128);
  k_gemm<2><<<g3, 256, 0, stream>>>(ABF, fwkb, nullptr, KKB, nullptr, nullptr, Cn, HIDn);
  k_gemm<0><<<g1, 256, 0, stream>>>(KKB, fwvb, KB, nullptr, nullptr, nullptr, HIDn, Cn);
  k_gemm<1><<<g1, 256, 0, stream>>>(ABF, fwrb, RR, nullptr, nullptr, nullptr, Cn, Cn);
  k_final<<<dim3(Tn / 32, Cn / 32, Bn), 256, 0, stream>>>(TOK, RR, KB, gamma2, out);
}